// Round 6
// baseline (580.001 us; speedup 1.0000x reference)
//
#include <hip/hip_runtime.h>
#include <hip/hip_bf16.h>
#include <stdint.h>

// Problem constants
#define B_   4
#define T_   1024
#define D_   1024
#define E_   8
#define FF_  2048
#define NT_  4096            // B*T tokens
#define LCAP 9472            // 8192 pairs + 128-pad headroom + 256 overread pad
#define NT1  (D_ / 32)       // 32 K-tiles, stage1 (BK=32)
#define NT2  (1024 / 32)     // 32 K-tiles per split-K half, stage2

typedef unsigned short u16;
typedef __attribute__((ext_vector_type(8))) short bf16x8;   // 8 bf16 = 4 VGPRs
typedef __attribute__((ext_vector_type(4))) float f32x4;

#define MFMA16(a, b, c) __builtin_amdgcn_mfma_f32_16x16x32_bf16((a), (b), (c), 0, 0, 0)

__device__ __forceinline__ u16 f2bf(float f) {
  union { float f; uint32_t u; } c; c.f = f;
  return (u16)((c.u + 0x7FFFu + ((c.u >> 16) & 1u)) >> 16);   // RNE
}

__device__ __forceinline__ void gl_lds16(const void* g, void* l) {
  __builtin_amdgcn_global_load_lds(
      (const __attribute__((address_space(1))) uint32_t*)g,
      (__attribute__((address_space(3))) uint32_t*)l, 16, 0, 0);
}

// ---------------- small kernels ----------------

__global__ __launch_bounds__(256) void k_init(int* __restrict__ tok, float* __restrict__ gate,
                                              int* __restrict__ cnt, int* __restrict__ cur) {
  int i = blockIdx.x * 256 + threadIdx.x;
  if (i < LCAP) { tok[i] = 0; gate[i] = 0.f; }
  if (i < E_)   { cnt[i] = 0; cur[i] = 0; }
}

// out = x (f32 copy) and xb = bf16(x), one pass over x
__global__ __launch_bounds__(256) void k_prep(const float4* __restrict__ x4,
                                              float4* __restrict__ out4,
                                              ushort4* __restrict__ xb4) {
  int i = blockIdx.x * 256 + threadIdx.x;   // exactly NT_*D_/4 threads
  float4 v = x4[i];
  out4[i] = v;
  ushort4 o; o.x = f2bf(v.x); o.y = f2bf(v.y); o.z = f2bf(v.z); o.w = f2bf(v.w);
  xb4[i] = o;
}

// one wave per token: 8 dot products of length 1024
__global__ __launch_bounds__(256) void k_router(const float* __restrict__ x,
                                                const float* __restrict__ rw,
                                                const float* __restrict__ rb,
                                                const float* __restrict__ temp,
                                                float* __restrict__ scores) {
  int wid  = (blockIdx.x * 256 + threadIdx.x) >> 6;   // token id
  int lane = threadIdx.x & 63;
  const float* xr = x + (size_t)wid * D_;
  float acc[E_];
  #pragma unroll
  for (int e = 0; e < E_; ++e) acc[e] = 0.f;
  for (int i = lane; i < D_; i += 64) {
    float xv = xr[i];
    #pragma unroll
    for (int e = 0; e < E_; ++e) acc[e] += xv * rw[e * D_ + i];
  }
  float inv = 1.0f / fmaxf(temp[0], 0.1f);
  #pragma unroll
  for (int e = 0; e < E_; ++e) {
    float v = acc[e];
    for (int off = 32; off; off >>= 1) v += __shfl_xor(v, off);
    if (lane == 0) scores[(size_t)wid * E_ + e] = (v + rb[e]) * inv;
  }
}

// one block per batch b; thread t owns token row [b,t]; 3 Sinkhorn iters + top-2
__global__ __launch_bounds__(1024) void k_sinkhorn(const float* __restrict__ scores,
                                                   float* __restrict__ tkg, int* __restrict__ tki,
                                                   int* __restrict__ cnt) {
  const int b = blockIdx.x, t = threadIdx.x;
  const int row = b * T_ + t;
  float s[E_];
  #pragma unroll
  for (int e = 0; e < E_; ++e) s[e] = scores[(size_t)row * E_ + e];

  __shared__ float red[16][E_];
  __shared__ int lcnt[E_];
  if (t < E_) lcnt[t] = 0;
  const int wid = t >> 6, lane = t & 63;

  for (int it = 0; it < 3; ++it) {
    float m = s[0];
    #pragma unroll
    for (int e = 1; e < E_; ++e) m = fmaxf(m, s[e]);
    float sum = 0.f;
    #pragma unroll
    for (int e = 0; e < E_; ++e) sum += expf(s[e] - m);
    float lse = m + logf(sum);
    #pragma unroll
    for (int e = 0; e < E_; ++e) s[e] -= lse;

    float cm[E_];
    #pragma unroll
    for (int e = 0; e < E_; ++e) {
      float v = s[e];
      for (int off = 32; off; off >>= 1) v = fmaxf(v, __shfl_xor(v, off));
      if (lane == 0) red[wid][e] = v;
    }
    __syncthreads();
    #pragma unroll
    for (int e = 0; e < E_; ++e) {
      float mm = red[0][e];
      for (int wv = 1; wv < 16; ++wv) mm = fmaxf(mm, red[wv][e]);
      cm[e] = mm;
    }
    __syncthreads();
    #pragma unroll
    for (int e = 0; e < E_; ++e) {
      float v = expf(s[e] - cm[e]);
      for (int off = 32; off; off >>= 1) v += __shfl_xor(v, off);
      if (lane == 0) red[wid][e] = v;
    }
    __syncthreads();
    #pragma unroll
    for (int e = 0; e < E_; ++e) {
      float ss = 0.f;
      for (int wv = 0; wv < 16; ++wv) ss += red[wv][e];
      s[e] -= cm[e] + logf(ss);
    }
    __syncthreads();
  }

  float g[E_]; float rs = 0.f;
  #pragma unroll
  for (int e = 0; e < E_; ++e) { g[e] = expf(s[e]); rs += g[e]; }
  float inv = 1.f / (rs + 1e-8f);
  #pragma unroll
  for (int e = 0; e < E_; ++e) g[e] *= inv;

  int i0 = 0; float v0 = g[0];
  #pragma unroll
  for (int e = 1; e < E_; ++e) if (g[e] > v0) { v0 = g[e]; i0 = e; }
  int i1 = -1; float v1 = -1e30f;
  #pragma unroll
  for (int e = 0; e < E_; ++e) if (e != i0 && g[e] > v1) { v1 = g[e]; i1 = e; }
  float den = 1.f / (v0 + v1 + 1e-8f);
  tkg[row * 2 + 0] = v0 * den; tki[row * 2 + 0] = i0;
  tkg[row * 2 + 1] = v1 * den; tki[row * 2 + 1] = i1;

  atomicAdd(&lcnt[i0], 1);
  atomicAdd(&lcnt[i1], 1);
  __syncthreads();
  if (t < E_) atomicAdd(&cnt[t], lcnt[t]);
}

__global__ void k_offsets(const int* __restrict__ cnt, int* __restrict__ segoff) {
  if (threadIdx.x == 0 && blockIdx.x == 0) {
    int run = 0;
    for (int e = 0; e < E_; ++e) { segoff[e] = run; run += ((cnt[e] + 127) >> 7) << 7; }
    segoff[E_] = run;
  }
}

__global__ __launch_bounds__(256) void k_scatter(const int* __restrict__ tki, const float* __restrict__ tkg,
                                                 const int* __restrict__ segoff, int* __restrict__ cur,
                                                 int* __restrict__ tok, float* __restrict__ gate) {
  int idx = blockIdx.x * 256 + threadIdx.x;    // 8192 pairs
  int row = idx >> 1;
  int e = tki[idx];
  float g = tkg[idx];
  int pos = atomicAdd(&cur[e], 1);
  int p = segoff[e] + pos;
  tok[p] = row;
  gate[p] = g;
}

// plain: f32 [z][R][C] -> bf16 [z][C][R]   (used for wo)
__global__ __launch_bounds__(256) void k_transpose(const float* __restrict__ in, u16* __restrict__ out,
                                                   int R, int C) {
  __shared__ __align__(16) u16 t[32][36];
  const size_t msz = (size_t)R * C;
  const float* A = in + blockIdx.z * msz;
  u16* O = out + blockIdx.z * msz;
  const int r0 = blockIdx.y * 32, c0 = blockIdx.x * 32;
  const int tid = threadIdx.x;
  {
    const int i = tid >> 3, j4 = (tid & 7) << 2;
    const float4 v = *(const float4*)(A + (size_t)(r0 + i) * C + c0 + j4);
    ushort4 pk; pk.x = f2bf(v.x); pk.y = f2bf(v.y); pk.z = f2bf(v.z); pk.w = f2bf(v.w);
    *(ushort4*)(&t[i][j4]) = pk;
  }
  __syncthreads();
  {
    const int j2 = tid & 15;
    #pragma unroll
    for (int it = 0; it < 2; ++it) {
      const int r = (tid >> 4) + it * 16;
      uint32_t pv = (uint32_t)t[2 * j2][r] | ((uint32_t)t[2 * j2 + 1][r] << 16);
      *(uint32_t*)(O + (size_t)(c0 + r) * R + r0 + 2 * j2) = pv;
    }
  }
}

// weights wg/wp: f32 [e][D][FF] -> bf16 interleaved A [e][4096][1024]:
// real f row goes to f' = (f>>4)*32 + (f&15) + woff  (woff: wg=0, wp=16)
__global__ __launch_bounds__(256) void k_transpose_w(const float* __restrict__ in,
                                                     u16* __restrict__ out, int woff) {
  __shared__ __align__(16) u16 t[32][36];
  const float* A = in + (size_t)blockIdx.z * D_ * FF_;
  u16* O = out + (size_t)blockIdx.z * 4096 * 1024;
  const int r0 = blockIdx.y * 32, c0 = blockIdx.x * 32;   // r0: d, c0: f
  const int tid = threadIdx.x;
  {
    const int i = tid >> 3, j4 = (tid & 7) << 2;
    const float4 v = *(const float4*)(A + (size_t)(r0 + i) * FF_ + c0 + j4);
    ushort4 pk; pk.x = f2bf(v.x); pk.y = f2bf(v.y); pk.z = f2bf(v.z); pk.w = f2bf(v.w);
    *(ushort4*)(&t[i][j4]) = pk;
  }
  __syncthreads();
  {
    const int j2 = tid & 15;
    #pragma unroll
    for (int it = 0; it < 2; ++it) {
      const int r = (tid >> 4) + it * 16;
      const int f = c0 + r;
      const int fp = ((f >> 4) << 5) + (f & 15) + woff;
      uint32_t pv = (uint32_t)t[2 * j2][r] | ((uint32_t)t[2 * j2 + 1][r] << 16);
      *(uint32_t*)(O + (size_t)fp * 1024 + r0 + 2 * j2) = pv;
    }
  }
}

// ---- GEMM LDS layout (per operand tile, 256 rows x BK=32): 16 rowblocks of
// 512 u16. u16 offset = rb*512 + lane*8; lane i holds row (i&15), 8k-chunk
// (i>>4). Fragment read = one linear ds_read_b128 (conflict-free, proven 0
// SQ_LDS_BANK_CONFLICT R2-R4). gl_lds16 staging: wave w stages rowblocks
// {2w, 2w+1}; global src for lane i = row (i&15), k-off (i>>4)*8.

// ---------------- stage 1: H = relu(X wg) * (X wp) ----------------
// A = interleaved wgwp (256 f' = 128 real f), B = X gathered by tok (256 p).
// 8 waves 2M x 4N: wave = 128 f' x 64 p.
__global__ __launch_bounds__(512, 2) void k_stage1(
    const u16* __restrict__ wa, const u16* __restrict__ xb,
    const int* __restrict__ tok, const int* __restrict__ segoff,
    u16* __restrict__ H) {
  const int raw = blockIdx.x;
  const int e   = raw & 7;           // XCD pin
  const int rem = raw >> 3;          // 0..255
  const int ft  = rem >> 4;          // 0..15
  const int pt2 = rem & 15;          // 0..15
  const int seg0 = segoff[e], segend = segoff[e + 1];
  if (pt2 * 256 >= segend - seg0) return;
  const int tid = threadIdx.x;
  const int lane = tid & 63;
  const int w = tid >> 6;
  const int lane15 = lane & 15, lchunk = lane >> 4;
  const int fw = w >> 2, pw = w & 3;

  __shared__ __align__(16) u16 LA[2][8192];
  __shared__ __align__(16) u16 LB[2][8192];   // 64 KB

  const int prow0 = seg0 + pt2 * 256;
  const u16* asrc0 = wa + (size_t)e * 4096 * 1024
                        + (size_t)(ft * 256 + 2 * w * 16 + lane15) * 1024 + lchunk * 8;
  const u16* asrc1 = asrc0 + 16 * 1024;
  const int tk0 = tok[prow0 + 2 * w * 16 + lane15];
  const int tk1 = tok[prow0 + 2 * w * 16 + 16 + lane15];
  const u16* bsrc0 = xb + (size_t)tk0 * D_ + lchunk * 8;
  const u16* bsrc1 = xb + (size_t)tk1 * D_ + lchunk * 8;
  const int dst0 = 2 * w * 512, dst1 = dst0 + 512;

  const f32x4 vz = {0.f, 0.f, 0.f, 0.f};
  f32x4 acc[8][4];
  #pragma unroll
  for (int m = 0; m < 8; ++m)
    #pragma unroll
    for (int n = 0; n < 4; ++n) acc[m][n] = vz;

#define ISSUE1(c, t) do { const int o_ = (t) * 32;          \
    gl_lds16(asrc0 + o_, &LA[c][dst0]);                     \
    gl_lds16(asrc1 + o_, &LA[c][dst1]);                     \
    gl_lds16(bsrc0 + o_, &LB[c][dst0]);                     \
    gl_lds16(bsrc1 + o_, &LB[c][dst1]); } while (0)

  ISSUE1(0, 0);
  #pragma unroll 1
  for (int t = 0; t < NT1; ++t) {
    const int c = t & 1;
    asm volatile("s_waitcnt vmcnt(0)" ::: "memory");   // tile t staged (mine)
    __builtin_amdgcn_s_barrier();                      // staged by all; c^1 free
    asm volatile("" ::: "memory");
    if (t + 1 < NT1) ISSUE1(c ^ 1, t + 1);
    const u16* la = LA[c];
    const u16* lb = LB[c];
    bf16x8 bv[4], av[4];
    #pragma unroll
    for (int n = 0; n < 4; ++n)
      bv[n] = *(const bf16x8*)(lb + (pw * 4 + n) * 512 + lane * 8);
    #pragma unroll
    for (int m = 0; m < 4; ++m)
      av[m] = *(const bf16x8*)(la + (fw * 8 + m) * 512 + lane * 8);
    __builtin_amdgcn_s_setprio(1);
    #pragma unroll
    for (int m = 0; m < 4; ++m)
      #pragma unroll
      for (int n = 0; n < 4; ++n)
        acc[m][n] = MFMA16(av[m], bv[n], acc[m][n]);
    __builtin_amdgcn_s_setprio(0);
    __builtin_amdgcn_s_barrier();                      // convoy barrier
    asm volatile("" ::: "memory");
    #pragma unroll
    for (int m = 0; m < 4; ++m)
      av[m] = *(const bf16x8*)(la + (fw * 8 + 4 + m) * 512 + lane * 8);
    __builtin_amdgcn_s_setprio(1);
    #pragma unroll
    for (int m = 0; m < 4; ++m)
      #pragma unroll
      for (int n = 0; n < 4; ++n)
        acc[4 + m][n] = MFMA16(av[m], bv[n], acc[4 + m][n]);
    __builtin_amdgcn_s_setprio(0);
  }
#undef ISSUE1

  // epilogue: m=2q is G, m=2q+1 is P of the same real f rows (interleaved A).
  // H[p][f]: lane's 4 acc regs are consecutive f -> packed 8B stores.
  const int jrow = lchunk * 4;
  #pragma unroll
  for (int q = 0; q < 4; ++q) {
    const int fcol = ft * 128 + fw * 64 + q * 16 + jrow;
    #pragma unroll
    for (int n = 0; n < 4; ++n) {
      const int prow = prow0 + pw * 64 + n * 16 + lane15;
      if (prow < segend) {
        union { uint2 v; u16 s[4]; } u;
        #pragma unroll
        for (int j = 0; j < 4; ++j)
          u.s[j] = f2bf(fmaxf(acc[2 * q][n][j], 0.f) * acc[2 * q + 1][n][j]);
        *(uint2*)(H + (size_t)prow * FF_ + fcol) = u.v;
      }
    }
  }
}

// ---------------- stage 2: O = (H @ wo) * gate, atomic += into out ----------------
// A = H (256 p rows), B = woT (256 d rows), K = 2048 split-K 2 x 1024.
__global__ __launch_bounds__(512, 2) void k_stage2(
    const u16* __restrict__ H, const u16* __restrict__ woT,
    const int* __restrict__ tok, const float* __restrict__ gate,
    const int* __restrict__ segoff, float* __restrict__ out) {
  const int raw = blockIdx.x;
  const int e   = raw & 7;
  const int rem = raw >> 3;          // 0..127
  const int ks  = rem & 1;
  const int pt2 = (rem >> 1) & 15;   // 0..15
  const int dt  = rem >> 5;          // 0..3
  const int seg0 = segoff[e], segend = segoff[e + 1];
  if (pt2 * 256 >= segend - seg0) return;
  const int tid = threadIdx.x;
  const int lane = tid & 63;
  const int w = tid >> 6;
  const int lane15 = lane & 15, lchunk = lane >> 4;
  const int ph = w >> 2, dw = w & 3;

  __shared__ __align__(16) u16 LA[2][8192];
  __shared__ __align__(16) u16 LB[2][8192];   // 64 KB
  __shared__ int   ltok[256];
  __shared__ float lgt[256];

  const int prow0 = seg0 + pt2 * 256;
  // FIX(R5 bug): a 256-row tile can cross this expert's 128-aligned segment
  // end into expert e+1's rows (real tokens, nonzero gates) -> those rows
  // added gate*(H @ WRONG expert's wo). Zero the gate outside [seg0,segend).
  if (tid < 256) {
    const int pr = prow0 + tid;
    ltok[tid] = tok[pr];
    lgt[tid] = (pr < segend) ? gate[pr] : 0.f;
  }

  const u16* asrc0 = H + (size_t)(prow0 + 2 * w * 16 + lane15) * FF_ + ks * 1024 + lchunk * 8;
  const u16* asrc1 = asrc0 + (size_t)16 * FF_;
  const u16* bsrc0 = woT + (size_t)e * D_ * FF_
                         + (size_t)(dt * 256 + 2 * w * 16 + lane15) * FF_ + ks * 1024 + lchunk * 8;
  const u16* bsrc1 = bsrc0 + (size_t)16 * FF_;
  const int dst0 = 2 * w * 512, dst1 = dst0 + 512;

  const f32x4 vz = {0.f, 0.f, 0.f, 0.f};
  f32x4 acc[8][4];
  #pragma unroll
  for (int m = 0; m < 8; ++m)
    #pragma unroll
    for (int n = 0; n < 4; ++n) acc[m][n] = vz;

#define ISSUE2(c, t) do { const int o_ = (t) * 32;          \
    gl_lds16(asrc0 + o_, &LA[c][dst0]);                     \
    gl_lds16(asrc1 + o_, &LA[c][dst1]);                     \
    gl_lds16(bsrc0 + o_, &LB[c][dst0]);                     \
    gl_lds16(bsrc1 + o_, &LB[c][dst1]); } while (0)

  ISSUE2(0, 0);
  #pragma unroll 1
  for (int t = 0; t < NT2; ++t) {
    const int c = t & 1;
    asm volatile("s_waitcnt vmcnt(0)" ::: "memory");
    __builtin_amdgcn_s_barrier();
    asm volatile("" ::: "memory");
    if (t + 1 < NT2) ISSUE2(c ^ 1, t + 1);
    const u16* la = LA[c];
    const u16* lb = LB[c];
    bf16x8 bv[4], av[4];
    #pragma unroll
    for (int n = 0; n < 4; ++n)
      bv[n] = *(const bf16x8*)(lb + (dw * 4 + n) * 512 + lane * 8);
    #pragma unroll
    for (int m = 0; m < 4; ++m)
      av[m] = *(const bf16x8*)(la + (ph * 8 + m) * 512 + lane * 8);
    __builtin_amdgcn_s_setprio(1);
    #pragma unroll
    for (int m = 0; m < 4; ++m)
      #pragma unroll
      for (int n = 0; n < 4; ++n)
        acc[m][n] = MFMA16(av[m], bv[n], acc[m][n]);
    __builtin_amdgcn_s_setprio(0);
    __builtin_amdgcn_s_barrier();
    asm volatile("" ::: "memory");
    #pragma unroll
    for (int m = 0; m < 4; ++m)
      av[m] = *(const bf16x8*)(la + (ph * 8 + 4 + m) * 512 + lane * 8);
    __builtin_amdgcn_s_setprio(1);
    #pragma unroll
    for (int m = 0; m < 4; ++m)
      #pragma unroll
      for (int n = 0; n < 4; ++n)
        acc[4 + m][n] = MFMA16(av[m], bv[n], acc[4 + m][n]);
    __builtin_amdgcn_s_setprio(0);
  }
#undef ISSUE2

  // epilogue: padding / out-of-segment rows have lgt==0 -> contribute 0.
  const int jrow = lchunk * 4;
  #pragma unroll
  for (int m = 0; m < 8; ++m) {
    #pragma unroll
    for (int n = 0; n < 4; ++n) {
      const int dcol = dt * 256 + dw * 64 + n * 16 + lane15;
      #pragma unroll
      for (int j = 0; j < 4; ++j) {
        const int pl = ph * 128 + m * 16 + jrow + j;
        unsafeAtomicAdd(&out[(size_t)ltok[pl] * D_ + dcol], lgt[pl] * acc[m][n][j]);
      }
    }
  }
}

// ---------------- host ----------------

extern "C" void kernel_launch(void* const* d_in, const int* in_sizes, int n_in,
                              void* d_out, int out_size, void* d_ws, size_t ws_size,
                              hipStream_t stream) {
  const float* x    = (const float*)d_in[0];
  const float* rw   = (const float*)d_in[1];
  const float* rb   = (const float*)d_in[2];
  const float* temp = (const float*)d_in[3];
  const float* wg   = (const float*)d_in[4];
  const float* wp   = (const float*)d_in[5];
  const float* wo   = (const float*)d_in[6];
  float* out = (float*)d_out;
  char* ws = (char*)d_ws;

  // workspace layout (bytes)
  const size_t O_XB  = 0;                                  // NT*D bf16        = 8,388,608
  const size_t O_WA  = 8388608;                            // E*4096*1024 bf16 = 67,108,864
  const size_t O_WOT = O_WA;                               // woT reuses wa after stage1
  const size_t O_H   = O_WA + 67108864;                    // LCAP*FF bf16     = 38,797,312
  const size_t O_SC  = O_H + (size_t)LCAP * FF_ * 2;
  const size_t O_TKG = O_SC + (size_t)NT_ * E_ * 4;
  const size_t O_TKI = O_TKG + (size_t)NT_ * 2 * 4;
  const size_t O_CNT = O_TKI + (size_t)NT_ * 2 * 4;
  const size_t O_CUR = O_CNT + 128;
  const size_t O_SEG = O_CUR + 128;
  const size_t O_TOK = O_SEG + 128;
  const size_t O_GTE = O_TOK + (size_t)LCAP * 4;
  const size_t REQ   = O_GTE + (size_t)LCAP * 4;           // ~114.6 MB
  if (ws_size < REQ) return;

  u16*   xb     = (u16*)(ws + O_XB);
  u16*   wa     = (u16*)(ws + O_WA);
  u16*   woT    = (u16*)(ws + O_WOT);
  u16*   Hbuf   = (u16*)(ws + O_H);
  float* scores = (float*)(ws + O_SC);
  float* tkg    = (float*)(ws + O_TKG);
  int*   tki    = (int*)(ws + O_TKI);
  int*   cnt    = (int*)(ws + O_CNT);
  int*   cur    = (int*)(ws + O_CUR);
  int*   segoff = (int*)(ws + O_SEG);
  int*   tok    = (int*)(ws + O_TOK);
  float* gate   = (float*)(ws + O_GTE);

  k_init<<<(LCAP + 255) / 256, 256, 0, stream>>>(tok, gate, cnt, cur);
  k_prep<<<(NT_ * D_ / 4) / 256, 256, 0, stream>>>((const float4*)x, (float4*)out, (ushort4*)xb);
  k_router<<<NT_ / 4, 256, 0, stream>>>(x, rw, rb, temp, scores);
  k_sinkhorn<<<B_, 1024, 0, stream>>>(scores, tkg, tki, cnt);
  k_offsets<<<1, 64, 0, stream>>>(cnt, segoff);
  k_scatter<<<(NT_ * 2) / 256, 256, 0, stream>>>(tki, tkg, segoff, cur, tok, gate);

  // wg,wp -> interleaved bf16 A [e][4096 f'][1024 d]
  k_transpose_w<<<dim3(FF_ / 32, D_ / 32, E_), 256, 0, stream>>>(wg, wa, 0);
  k_transpose_w<<<dim3(FF_ / 32, D_ / 32, E_), 256, 0, stream>>>(wp, wa, 16);

  k_stage1<<<16 * 16 * E_, 512, 0, stream>>>(wa, xb, tok, segoff, Hbuf);

  // wo: [FF][D] -> [D][FF]  (overwrites wa region, dead after stage1)
  k_transpose<<<dim3(D_ / 32, FF_ / 32, E_), 256, 0, stream>>>(wo, woT, FF_, D_);

  k_stage2<<<4 * 16 * 2 * E_, 512, 0, stream>>>(Hbuf, woT, tok, gate, segoff, out);
}